// Round 3
// baseline (1443.753 us; speedup 1.0000x reference)
//
#include <hip/hip_runtime.h>
#include <math.h>

// Problem constants
constexpr int BB  = 64;    // batch
constexpr int CIc = 3;     // image channels
constexpr int HIc = 96, WIc = 96;
constexpr int Gc  = 8, HGc = 16, WGc = 16;
constexpr int HIDc = 18432;      // 128*12*12
constexpr int HIDLINc = 512;

// Repacked weights live in a device global (ws regions are all ping-ponged).
// Layout per conv: [ci][ocChunk][oc(32)][12 (9 weights + 3 pad)]
__device__ __attribute__((aligned(16))) float g_wrep[382080];
// offsets (floats): w1a 0, w1b 1152, w2a 13440, w2b 38016, w3a 87168, w3b 185472
constexpr int OFS_W1A = 0;
constexpr int OFS_W1B = 1152;
constexpr int OFS_W2A = 13440;
constexpr int OFS_W2B = 38016;
constexpr int OFS_W3A = 87168;
constexpr int OFS_W3B = 185472;

__global__ void repack_w(const float* __restrict__ w, int COUT, int CIN, int ofs)
{
    int idx = blockIdx.x * blockDim.x + threadIdx.x;
    int total = COUT * CIN * 9;
    if (idx >= total) return;
    int k = idx % 9; int t = idx / 9;
    int ci = t % CIN; int oc = t / CIN;
    int chunk = oc >> 5, o = oc & 31;
    int nchunk = COUT >> 5;
    g_wrep[ofs + (((ci * nchunk + chunk) * 32 + o) * 12 + k)] = w[idx];
}

// Force a pointer into SGPRs (wave-uniform) so weight loads get saddr form.
__device__ inline const float* uptr(const float* p)
{
    uint32_t lo = __builtin_amdgcn_readfirstlane((uint32_t)(uintptr_t)p);
    uint32_t hi = __builtin_amdgcn_readfirstlane((uint32_t)((uintptr_t)p >> 32));
    return (const float*)(((uint64_t)hi << 32) | (uint64_t)lo);
}

// ---------------------------------------------------------------------------
// conv3x3 v2: per block = (spatial tile) x (32-oc chunk) x (split-K slice).
// Input staged in LDS in CBLK-channel chunks; weights from repacked global
// via uniform base + constant float4 offsets (saddr, zero VALU per load).
// SPLIT=true  -> write bias-free partials [KS][B][COUT][H][W]
// SPLIT=false -> bias + ReLU direct output
// ---------------------------------------------------------------------------
template<int CIN, int COUT, int H, int W, int TH, int TW, int CBLK, int KS, bool SPLIT>
__global__ __launch_bounds__(TH * TW)
void conv3x3_v2(const float* __restrict__ in, int w2ofs,
                const float* __restrict__ bias, float* __restrict__ out)
{
    constexpr int NCHUNK = COUT / 32;
    constexpr int CPB = CIN / KS;          // input channels per block
    constexpr int NTX = W / TW;
    constexpr int SH = TH + 2, SW = TW + 2;

    const int tx = blockIdx.x % NTX, ty = blockIdx.x / NTX;
    const int b  = blockIdx.y;
    const int chunk = blockIdx.z / KS;
    const int ks    = blockIdx.z % KS;
    const int coutBase = chunk * 32;
    const int cinBase  = ks * CPB;
    const int tid = threadIdx.x;
    const int px = tid % TW, py = tid / TW;
    const int ox = tx * TW, oy = ty * TH;

    __shared__ float s_in[CBLK][SH][SW];

    float acc[32];
    if constexpr (SPLIT) {
#pragma unroll
        for (int oc = 0; oc < 32; ++oc) acc[oc] = 0.0f;
    } else {
#pragma unroll
        for (int oc = 0; oc < 32; ++oc) acc[oc] = bias[coutBase + oc];
    }

    for (int cb = 0; cb < CPB; cb += CBLK) {
        __syncthreads();
        constexpr int TOT = CBLK * SH * SW;
        for (int idx = tid; idx < TOT; idx += TH * TW) {
            int ci  = idx / (SH * SW);
            int rem = idx - ci * (SH * SW);
            int yy = rem / SW;
            int xx = rem - yy * SW;
            int gy = oy + yy - 1, gx = ox + xx - 1;
            float v = 0.0f;
            if (gy >= 0 && gy < H && gx >= 0 && gx < W)
                v = in[((size_t)(b * CIN + cinBase + cb + ci) * H + gy) * W + gx];
            s_in[ci][yy][xx] = v;
        }
        __syncthreads();

        for (int ci = 0; ci < CBLK; ++ci) {
            float v[9];
#pragma unroll
            for (int dy = 0; dy < 3; ++dy)
#pragma unroll
                for (int dx = 0; dx < 3; ++dx)
                    v[dy * 3 + dx] = s_in[ci][py + dy][px + dx];

            const int ciAbs = cinBase + cb + ci;
            const float4* wb4 = (const float4*)uptr(
                g_wrep + w2ofs + (size_t)(ciAbs * NCHUNK + chunk) * 32 * 12);
#pragma unroll
            for (int oc = 0; oc < 32; ++oc) {
                float4 wa = wb4[oc * 3 + 0];
                float4 wb = wb4[oc * 3 + 1];
                float4 wc = wb4[oc * 3 + 2];
                float a = acc[oc];
                a = fmaf(v[0], wa.x, a);
                a = fmaf(v[1], wa.y, a);
                a = fmaf(v[2], wa.z, a);
                a = fmaf(v[3], wa.w, a);
                a = fmaf(v[4], wb.x, a);
                a = fmaf(v[5], wb.y, a);
                a = fmaf(v[6], wb.z, a);
                a = fmaf(v[7], wb.w, a);
                a = fmaf(v[8], wc.x, a);
                acc[oc] = a;
            }
        }
    }

    if constexpr (SPLIT) {
#pragma unroll
        for (int oc = 0; oc < 32; ++oc) {
            out[(((size_t)ks * BB + b) * COUT + coutBase + oc) * (H * W) +
                (oy + py) * W + ox + px] = acc[oc];
        }
    } else {
#pragma unroll
        for (int oc = 0; oc < 32; ++oc) {
            out[((size_t)(b * COUT + coutBase + oc) * H + oy + py) * W + ox + px] =
                fmaxf(acc[oc], 0.0f);
        }
    }
}

// Sum split-K partials + bias + ReLU
template<int C, int H, int W, int KS>
__global__ void conv_reduce(const float* __restrict__ partial,
                            const float* __restrict__ bias,
                            float* __restrict__ out)
{
    constexpr int TOTAL = BB * C * H * W;
    int idx = blockIdx.x * blockDim.x + threadIdx.x;
    if (idx >= TOTAL) return;
    int c = (idx / (H * W)) % C;
    float s = bias[c];
#pragma unroll
    for (int k = 0; k < KS; ++k)
        s += partial[(size_t)k * TOTAL + idx];
    out[idx] = fmaxf(s, 0.0f);
}

// ---------------------------------------------------------------------------
// Max pool KxK, stride K
// ---------------------------------------------------------------------------
template<int C, int H, int W, int K>
__global__ void maxpool_k(const float* __restrict__ in, float* __restrict__ out)
{
    constexpr int HO = H / K, WO = W / K;
    int idx = blockIdx.x * blockDim.x + threadIdx.x;
    constexpr int TOTAL = BB * C * HO * WO;
    if (idx >= TOTAL) return;
    int wo = idx % WO; int t = idx / WO;
    int ho = t % HO; t /= HO;
    int c = t % C; int b = t / C;
    const float* p = in + ((size_t)(b * C + c) * H + ho * K) * W + wo * K;
    float m = -INFINITY;
#pragma unroll
    for (int i = 0; i < K; ++i)
#pragma unroll
        for (int j = 0; j < K; ++j)
            m = fmaxf(m, p[i * W + j]);
    out[idx] = m;
}

// ---------------------------------------------------------------------------
// lin1: (64, 18432) @ (18432, 512), split-K partials.
// ---------------------------------------------------------------------------
constexpr int KSPLIT = 64;              // 18432 / 64 = 288 per split
__global__ __launch_bounds__(256)
void lin1_partial(const float* __restrict__ x, const float* __restrict__ w,
                  float* __restrict__ partial)
{
    const int j  = threadIdx.x % 64;
    const int bg = threadIdx.x / 64;          // 0..3
    const int jBase = blockIdx.x * 64;        // 8 tiles of 64
    const int k  = blockIdx.y;                // 0..63
    const int i0 = k * 288;

    __shared__ float s_x[32][64];

    float acc[16];
#pragma unroll
    for (int u = 0; u < 16; ++u) acc[u] = 0.0f;

    for (int ib = 0; ib < 288; ib += 32) {
        __syncthreads();
        {
            int lb = threadIdx.x / 4;           // b 0..63
            int lo = (threadIdx.x % 4) * 8;     // ii 0,8,16,24
            const float* src = x + (size_t)lb * HIDc + i0 + ib + lo;
            float4 a0 = *(const float4*)(src);
            float4 a1 = *(const float4*)(src + 4);
            float tmp[8] = {a0.x, a0.y, a0.z, a0.w, a1.x, a1.y, a1.z, a1.w};
#pragma unroll
            for (int r = 0; r < 8; ++r) s_x[lo + r][lb] = tmp[r];
        }
        __syncthreads();

        for (int ii = 0; ii < 32; ++ii) {
            float wv = w[(size_t)(i0 + ib + ii) * HIDLINc + jBase + j];
            const float4* xp = (const float4*)&s_x[ii][bg * 16];
            float4 x0 = xp[0], x1 = xp[1], x2 = xp[2], x3 = xp[3];
            acc[0]  = fmaf(x0.x, wv, acc[0]);
            acc[1]  = fmaf(x0.y, wv, acc[1]);
            acc[2]  = fmaf(x0.z, wv, acc[2]);
            acc[3]  = fmaf(x0.w, wv, acc[3]);
            acc[4]  = fmaf(x1.x, wv, acc[4]);
            acc[5]  = fmaf(x1.y, wv, acc[5]);
            acc[6]  = fmaf(x1.z, wv, acc[6]);
            acc[7]  = fmaf(x1.w, wv, acc[7]);
            acc[8]  = fmaf(x2.x, wv, acc[8]);
            acc[9]  = fmaf(x2.y, wv, acc[9]);
            acc[10] = fmaf(x2.z, wv, acc[10]);
            acc[11] = fmaf(x2.w, wv, acc[11]);
            acc[12] = fmaf(x3.x, wv, acc[12]);
            acc[13] = fmaf(x3.y, wv, acc[13]);
            acc[14] = fmaf(x3.z, wv, acc[14]);
            acc[15] = fmaf(x3.w, wv, acc[15]);
        }
    }

#pragma unroll
    for (int u = 0; u < 16; ++u) {
        int b = bg * 16 + u;
        partial[((size_t)k * 64 + b) * HIDLINc + jBase + j] = acc[u];
    }
}

__global__ void lin1_reduce(const float* __restrict__ partial,
                            const float* __restrict__ bias,
                            float* __restrict__ x1)
{
    int idx = blockIdx.x * blockDim.x + threadIdx.x;  // 64*512
    if (idx >= 64 * HIDLINc) return;
    int j = idx % HIDLINc;
    float s = 0.0f;
    for (int k = 0; k < KSPLIT; ++k)
        s += partial[(size_t)k * 64 * HIDLINc + idx];
    x1[idx] = fmaxf(s + bias[j], 0.0f);
}

// ---------------------------------------------------------------------------
// lin2: (64,512) @ (512,512) + bias + relu
// ---------------------------------------------------------------------------
__global__ __launch_bounds__(256)
void lin2_k(const float* __restrict__ x1, const float* __restrict__ w,
            const float* __restrict__ bias, float* __restrict__ x2)
{
    const int j  = threadIdx.x % 64;
    const int bl = threadIdx.x / 64;          // 0..3
    const int jBase = blockIdx.x * 64;        // 8
    const int b = blockIdx.y * 4 + bl;        // 16 groups of 4

    __shared__ float s_x[4][HIDLINc];
    for (int idx = threadIdx.x; idx < 4 * HIDLINc; idx += 256)
        s_x[idx / HIDLINc][idx % HIDLINc] =
            x1[(size_t)(blockIdx.y * 4 + idx / HIDLINc) * HIDLINc + idx % HIDLINc];
    __syncthreads();

    float acc = 0.0f;
    for (int i = 0; i < HIDLINc; ++i)
        acc = fmaf(s_x[bl][i], w[(size_t)i * HIDLINc + jBase + j], acc);
    x2[(size_t)b * HIDLINc + jBase + j] = fmaxf(acc + bias[jBase + j], 0.0f);
}

// ---------------------------------------------------------------------------
// lin3: (64,512) @ (512,24) + bias
// ---------------------------------------------------------------------------
__global__ void lin3_k(const float* __restrict__ x2, const float* __restrict__ w,
                       const float* __restrict__ bias, float* __restrict__ prep)
{
    int idx = blockIdx.x * blockDim.x + threadIdx.x;
    if (idx >= 64 * 24) return;
    int j = idx % 24, b = idx / 24;
    float acc = bias[j];
    for (int i = 0; i < HIDLINc; ++i)
        acc = fmaf(x2[(size_t)b * HIDLINc + i], w[i * 24 + j], acc);
    prep[idx] = acc;
}

// ---------------------------------------------------------------------------
// Head: means/sigmas/sample/points.  round = half-to-even (rintf)
// ---------------------------------------------------------------------------
__global__ void head_k(const float* __restrict__ prep, const float* __restrict__ noise,
                       float* __restrict__ outMeans, float* __restrict__ outSigmas,
                       int* __restrict__ pts)
{
    int id = blockIdx.x * blockDim.x + threadIdx.x;
    if (id >= BB * Gc) return;
    float m0 = prep[id * 3 + 0];
    float m1 = prep[id * 3 + 1];
    float sraw = prep[id * 3 + 2];
    float s = sraw + 2.0f;                       // SIGMA_BOOST
    float sig = fmaxf(s, 0.0f) + log1pf(expf(-fabsf(s)));
    sig += 1e-7f;                                // EPS
    float sg = sig * 95.0f;                      // (HI-1) == (WI-1)
    outMeans[id * 2 + 0] = m0;
    outMeans[id * 2 + 1] = m1;
    outSigmas[id * 2 + 0] = sg;
    outSigmas[id * 2 + 1] = sg;
    float sa0 = m0 + sg * noise[id * 2 + 0];
    float sa1 = m1 + sg * noise[id * 2 + 1];
    float t0 = 1.0f / (1.0f + expf(-sa0));
    float t1 = 1.0f / (1.0f + expf(-sa1));
    pts[id * 2 + 0] = (int)rintf(t0 * 79.0f);    // HI-HG-1
    pts[id * 2 + 1] = (int)rintf(t1 * 79.0f);    // WI-WG-1
}

// ---------------------------------------------------------------------------
// Patch extraction: copy (3,16,16) patch per (b,g)
// ---------------------------------------------------------------------------
__global__ __launch_bounds__(256)
void patch_k(const float* __restrict__ image, const int* __restrict__ pts,
             float* __restrict__ outR)
{
    int id = blockIdx.x;                  // b*G + g
    int b = id / Gc;
    int p0 = pts[id * 2 + 0];
    int p1 = pts[id * 2 + 1];
    for (int idx = threadIdx.x; idx < CIc * HGc * WGc; idx += 256) {
        int c = idx / (HGc * WGc), rem = idx % (HGc * WGc);
        int hh = rem / WGc, ww = rem % WGc;
        outR[(size_t)id * (CIc * HGc * WGc) + idx] =
            image[((size_t)(b * CIc + c) * HIc + p0 + hh) * WIc + p1 + ww];
    }
}

// ---------------------------------------------------------------------------
extern "C" void kernel_launch(void* const* d_in, const int* in_sizes, int n_in,
                              void* d_out, int out_size, void* d_ws, size_t ws_size,
                              hipStream_t stream)
{
    const float* image = (const float*)d_in[0];
    const float* noise = (const float*)d_in[1];
    const float* w1a = (const float*)d_in[2];
    const float* b1a = (const float*)d_in[3];
    const float* w1b = (const float*)d_in[4];
    const float* b1b = (const float*)d_in[5];
    const float* w2a = (const float*)d_in[6];
    const float* b2a = (const float*)d_in[7];
    const float* w2b = (const float*)d_in[8];
    const float* b2b = (const float*)d_in[9];
    const float* w3a = (const float*)d_in[10];
    const float* b3a = (const float*)d_in[11];
    const float* w3b = (const float*)d_in[12];
    const float* b3b = (const float*)d_in[13];
    const float* wl1 = (const float*)d_in[14];
    const float* bl1 = (const float*)d_in[15];
    const float* wl2 = (const float*)d_in[16];
    const float* bl2 = (const float*)d_in[17];
    const float* wl3 = (const float*)d_in[18];
    const float* bl3 = (const float*)d_in[19];

    float* out = (float*)d_out;
    float* ws  = (float*)d_ws;

    // Workspace layout (floats): two big regions A,B of 18,874,368 floats.
    constexpr size_t BIGF = (size_t)BB * 32 * HIc * WIc;   // 18,874,368 floats
    constexpr size_t MF = 1u << 20;
    float* A  = ws;
    float* Bf = ws + BIGF;
    float* t0   = A;                 // pool1 out      (1,179,648)
    float* t1   = A + 2 * MF;        // conv2a out     (2,359,296)
    float* t2   = A + 5 * MF;        // conv2b out     (2,359,296)
    float* t3   = A + 8 * MF;        // pool2 out        (589,824)
    float* t4   = A + 9 * MF;        // conv3a out     (1,179,648)
    float* t5   = A + 11 * MF;       // conv3b out / x (1,179,648)
    float* part = A + 13 * MF;       // lin1 partials  (2,097,152)
    float* x1   = A + 16 * MF;       // 32768
    float* x2   = x1 + 64 * HIDLINc; // 32768
    float* prep = x2 + 64 * HIDLINc; // 1536
    int*   pts  = (int*)(prep + 2048);

    // Repack all conv weights into g_wrep (padded-12, ci-major)
    repack_w<<<(32 * 3 * 9 + 255) / 256, 256, 0, stream>>>(w1a, 32, 3, OFS_W1A);
    repack_w<<<(32 * 32 * 9 + 255) / 256, 256, 0, stream>>>(w1b, 32, 32, OFS_W1B);
    repack_w<<<(64 * 32 * 9 + 255) / 256, 256, 0, stream>>>(w2a, 64, 32, OFS_W2A);
    repack_w<<<(64 * 64 * 9 + 255) / 256, 256, 0, stream>>>(w2b, 64, 64, OFS_W2B);
    repack_w<<<(128 * 64 * 9 + 255) / 256, 256, 0, stream>>>(w3a, 128, 64, OFS_W3A);
    repack_w<<<(128 * 128 * 9 + 255) / 256, 256, 0, stream>>>(w3b, 128, 128, OFS_W3B);

    // conv1a: image(64,3,96,96) -> A(64,32,96,96)
    conv3x3_v2<3, 32, 96, 96, 8, 32, 3, 1, false>
        <<<dim3(36, 64, 1), 256, 0, stream>>>(image, OFS_W1A, b1a, A);
    // conv1b: A -> B (64,32,96,96)
    conv3x3_v2<32, 32, 96, 96, 8, 32, 8, 1, false>
        <<<dim3(36, 64, 1), 256, 0, stream>>>(A, OFS_W1B, b1b, Bf);
    // pool 4x4: B -> t0 (64,32,24,24)
    maxpool_k<32, 96, 96, 4>
        <<<(BB * 32 * 24 * 24 + 255) / 256, 256, 0, stream>>>(Bf, t0);

    // conv2a: t0 -> partial(B) -> t1 (64,64,24,24); KS=2
    conv3x3_v2<32, 64, 24, 24, 8, 24, 8, 2, true>
        <<<dim3(3, 64, 2 * 2), 192, 0, stream>>>(t0, OFS_W2A, nullptr, Bf);
    conv_reduce<64, 24, 24, 2>
        <<<(BB * 64 * 576 + 255) / 256, 256, 0, stream>>>(Bf, b2a, t1);

    // conv2b: t1 -> partial(B) -> t2; KS=2
    conv3x3_v2<64, 64, 24, 24, 8, 24, 8, 2, true>
        <<<dim3(3, 64, 2 * 2), 192, 0, stream>>>(t1, OFS_W2B, nullptr, Bf);
    conv_reduce<64, 24, 24, 2>
        <<<(BB * 64 * 576 + 255) / 256, 256, 0, stream>>>(Bf, b2b, t2);

    // pool 2x2: t2 -> t3 (64,64,12,12)
    maxpool_k<64, 24, 24, 2>
        <<<(BB * 64 * 12 * 12 + 255) / 256, 256, 0, stream>>>(t2, t3);

    // conv3a: t3 -> partial(B) -> t4 (64,128,12,12); KS=4
    conv3x3_v2<64, 128, 12, 12, 12, 12, 8, 4, true>
        <<<dim3(1, 64, 4 * 4), 144, 0, stream>>>(t3, OFS_W3A, nullptr, Bf);
    conv_reduce<128, 12, 12, 4>
        <<<(BB * 128 * 144 + 255) / 256, 256, 0, stream>>>(Bf, b3a, t4);

    // conv3b: t4 -> partial(B) -> t5; KS=4
    conv3x3_v2<128, 128, 12, 12, 12, 12, 8, 4, true>
        <<<dim3(1, 64, 4 * 4), 144, 0, stream>>>(t4, OFS_W3B, nullptr, Bf);
    conv_reduce<128, 12, 12, 4>
        <<<(BB * 128 * 144 + 255) / 256, 256, 0, stream>>>(Bf, b3b, t5);

    // lin1: x @ wl1 (+bl1, relu) via split-K
    lin1_partial<<<dim3(8, KSPLIT), 256, 0, stream>>>(t5, wl1, part);
    lin1_reduce<<<(64 * HIDLINc + 255) / 256, 256, 0, stream>>>(part, bl1, x1);
    // lin2
    lin2_k<<<dim3(8, 16), 256, 0, stream>>>(x1, wl2, bl2, x2);
    // lin3 -> prep (64,24)
    lin3_k<<<6, 256, 0, stream>>>(x2, wl3, bl3, prep);
    // head -> means/sigmas into out, pts into ws
    head_k<<<2, 256, 0, stream>>>(prep, noise,
                                  out + (size_t)BB * Gc * CIc * HGc * WGc,
                                  out + (size_t)BB * Gc * CIc * HGc * WGc + BB * Gc * 2,
                                  pts);
    // patch extraction -> out[0 .. 393216)
    patch_k<<<BB * Gc, 256, 0, stream>>>(image, pts, out);
}

// Round 4
// 1011.706 us; speedup vs baseline: 1.4270x; 1.4270x over previous
//
#include <hip/hip_runtime.h>
#include <math.h>

// Problem constants
constexpr int BB  = 64;    // batch
constexpr int CIc = 3;     // image channels
constexpr int HIc = 96, WIc = 96;
constexpr int Gc  = 8, HGc = 16, WGc = 16;
constexpr int HIDc = 18432;      // 128*12*12
constexpr int HIDLINc = 512;

// ---------------------------------------------------------------------------
// Direct 3x3 conv (pad=1, stride=1) + bias + ReLU.  (conv1a only)
// ---------------------------------------------------------------------------
template<int CIN, int COUT, int H, int W, int TH, int TW, int CBLK>
__global__ __launch_bounds__(TH * TW)
void conv3x3_relu(const float* __restrict__ in, const float* __restrict__ wgt,
                  const float* __restrict__ bias, float* __restrict__ out)
{
    constexpr int NTX = W / TW;
    const int tile = blockIdx.x;
    const int tx = tile % NTX, ty = tile / NTX;
    const int b  = blockIdx.y;
    const int coutBase = blockIdx.z * 32;
    const int tid = threadIdx.x;
    const int px = tid % TW, py = tid / TW;
    const int ox = tx * TW, oy = ty * TH;

    __shared__ float s_in[CBLK][TH + 2][TW + 2];

    float acc[32];
#pragma unroll
    for (int oc = 0; oc < 32; ++oc) acc[oc] = bias[coutBase + oc];

    for (int cb = 0; cb < CIN; cb += CBLK) {
        __syncthreads();
        constexpr int TOT = CBLK * (TH + 2) * (TW + 2);
        for (int idx = tid; idx < TOT; idx += TH * TW) {
            int ci  = idx / ((TH + 2) * (TW + 2));
            int rem = idx % ((TH + 2) * (TW + 2));
            int yy = rem / (TW + 2), xx = rem % (TW + 2);
            int gy = oy + yy - 1, gx = ox + xx - 1;
            float v = 0.0f;
            if (gy >= 0 && gy < H && gx >= 0 && gx < W)
                v = in[((size_t)(b * CIN + cb + ci) * H + gy) * W + gx];
            s_in[ci][yy][xx] = v;
        }
        __syncthreads();

        for (int ci = 0; ci < CBLK; ++ci) {
            float v[9];
#pragma unroll
            for (int dy = 0; dy < 3; ++dy)
#pragma unroll
                for (int dx = 0; dx < 3; ++dx)
                    v[dy * 3 + dx] = s_in[ci][py + dy][px + dx];

#pragma unroll
            for (int oc = 0; oc < 32; ++oc) {
                const float* w9 =
                    wgt + ((size_t)(coutBase + oc) * CIN + (cb + ci)) * 9;
#pragma unroll
                for (int k = 0; k < 9; ++k)
                    acc[oc] = fmaf(v[k], w9[k], acc[oc]);
            }
        }
    }

#pragma unroll
    for (int oc = 0; oc < 32; ++oc) {
        out[((size_t)(b * COUT + coutBase + oc) * H + oy + py) * W + ox + px] =
            fmaxf(acc[oc], 0.0f);
    }
}

// ---------------------------------------------------------------------------
// conv1b_v3: CIN=COUT=32, H=W=96.
// Block: 192 thr = 16 x-lanes x 12 y-groups; thread: 8 rows x 8 oc (64 acc).
// Weights for the 8-oc chunk staged once in LDS (broadcast reads, amortized
// over 8 pixels). Input staged column-major [18][100] so per-ci values are
// 6 x ds_read_b128 + 3 x ds_read_b64, evenly bank-distributed.
// Grid: (6 x-tiles, 64 batch, 4 oc-chunks)
// ---------------------------------------------------------------------------
__global__ __launch_bounds__(192)
void conv1b_v3(const float* __restrict__ in, const float* __restrict__ wgt,
               const float* __restrict__ bias, float* __restrict__ out)
{
    const int tid = threadIdx.x;
    const int tx  = tid & 15;
    const int tyg = tid >> 4;            // 0..11
    const int y0  = tyg * 8;
    const int ox  = blockIdx.x * 16;
    const int b   = blockIdx.y;
    const int ocBase = blockIdx.z * 8;

    __shared__ float s_w[32][8][12];     // [ci][oc][k]  12,288 B (k 9..11 unused)
    __shared__ float s_in[2][18][100];   // [ci2][col][row] 14,400 B

    // stage the chunk's weights once: src layout [oc][ci][9]
    for (int idx = tid; idx < 32 * 8 * 9; idx += 192) {
        int k  = idx % 9;
        int ci = (idx / 9) % 32;
        int oc = idx / 288;
        s_w[ci][oc][k] = wgt[((size_t)(ocBase + oc) * 32 + ci) * 9 + k];
    }

    float acc[8][8];
#pragma unroll
    for (int o = 0; o < 8; ++o)
#pragma unroll
        for (int r = 0; r < 8; ++r) acc[o][r] = 0.0f;

    for (int cb = 0; cb < 32; cb += 2) {
        __syncthreads();     // also covers the weight staging on first iter
        for (int idx = tid; idx < 2 * 98 * 18; idx += 192) {
            int cl = idx % 18;
            int rw = (idx / 18) % 98;
            int c2 = idx / (98 * 18);
            int gy = rw - 1, gx = ox + cl - 1;
            float v = 0.0f;
            if (gy >= 0 && gy < 96 && gx >= 0 && gx < 96)
                v = in[((size_t)(b * 32 + cb + c2) * 96 + gy) * 96 + gx];
            s_in[c2][cl][rw] = v;
        }
        __syncthreads();

#pragma unroll
        for (int c2 = 0; c2 < 2; ++c2) {
            float va[3][10];
#pragma unroll
            for (int cl = 0; cl < 3; ++cl) {
                const float4* p = (const float4*)&s_in[c2][tx + cl][y0];
                float4 lo = p[0], hi = p[1];
                float2 tl = *(const float2*)&s_in[c2][tx + cl][y0 + 8];
                va[cl][0] = lo.x; va[cl][1] = lo.y; va[cl][2] = lo.z; va[cl][3] = lo.w;
                va[cl][4] = hi.x; va[cl][5] = hi.y; va[cl][6] = hi.z; va[cl][7] = hi.w;
                va[cl][8] = tl.x; va[cl][9] = tl.y;
            }
            const int ci = cb + c2;
#pragma unroll
            for (int o = 0; o < 8; ++o) {
                const float4* wp = (const float4*)&s_w[ci][o][0];
                float4 w0 = wp[0], w1 = wp[1];
                float  w8 = s_w[ci][o][8];
#pragma unroll
                for (int r = 0; r < 8; ++r) {
                    float a = acc[o][r];
                    a = fmaf(w0.x, va[0][r + 0], a);
                    a = fmaf(w0.y, va[1][r + 0], a);
                    a = fmaf(w0.z, va[2][r + 0], a);
                    a = fmaf(w0.w, va[0][r + 1], a);
                    a = fmaf(w1.x, va[1][r + 1], a);
                    a = fmaf(w1.y, va[2][r + 1], a);
                    a = fmaf(w1.z, va[0][r + 2], a);
                    a = fmaf(w1.w, va[1][r + 2], a);
                    a = fmaf(w8,   va[2][r + 2], a);
                    acc[o][r] = a;
                }
            }
        }
    }

#pragma unroll
    for (int o = 0; o < 8; ++o) {
        float bv = bias[ocBase + o];
#pragma unroll
        for (int r = 0; r < 8; ++r) {
            out[((size_t)(b * 32 + ocBase + o) * 96 + y0 + r) * 96 + ox + tx] =
                fmaxf(acc[o][r] + bv, 0.0f);
        }
    }
}

// ---------------------------------------------------------------------------
// Split-K direct 3x3 conv (round-2 form): partials [KS][B][COUT][H][W].
// ---------------------------------------------------------------------------
template<int CIN, int COUT, int H, int W, int TH, int TW, int KS>
__global__ __launch_bounds__(TH * TW)
void conv3x3_split(const float* __restrict__ in, const float* __restrict__ wgt,
                   float* __restrict__ partial)
{
    constexpr int CBLK = CIN / KS;
    constexpr int NTX = W / TW;
    const int tx = blockIdx.x % NTX, ty = blockIdx.x / NTX;
    const int b  = blockIdx.y;
    const int chunk = blockIdx.z / KS;
    const int ks    = blockIdx.z % KS;
    const int coutBase = chunk * 32;
    const int cinBase  = ks * CBLK;
    const int tid = threadIdx.x;
    const int px = tid % TW, py = tid / TW;
    const int ox = tx * TW, oy = ty * TH;

    __shared__ float s_in[CBLK][TH + 2][TW + 2];

    constexpr int TOT = CBLK * (TH + 2) * (TW + 2);
    for (int idx = tid; idx < TOT; idx += TH * TW) {
        int ci  = idx / ((TH + 2) * (TW + 2));
        int rem = idx % ((TH + 2) * (TW + 2));
        int yy = rem / (TW + 2), xx = rem % (TW + 2);
        int gy = oy + yy - 1, gx = ox + xx - 1;
        float v = 0.0f;
        if (gy >= 0 && gy < H && gx >= 0 && gx < W)
            v = in[((size_t)(b * CIN + cinBase + ci) * H + gy) * W + gx];
        s_in[ci][yy][xx] = v;
    }
    __syncthreads();

    float acc[32];
#pragma unroll
    for (int oc = 0; oc < 32; ++oc) acc[oc] = 0.0f;

    for (int ci = 0; ci < CBLK; ++ci) {
        float v[9];
#pragma unroll
        for (int dy = 0; dy < 3; ++dy)
#pragma unroll
            for (int dx = 0; dx < 3; ++dx)
                v[dy * 3 + dx] = s_in[ci][py + dy][px + dx];

#pragma unroll
        for (int oc = 0; oc < 32; ++oc) {
            const float* w9 =
                wgt + ((size_t)(coutBase + oc) * CIN + (cinBase + ci)) * 9;
#pragma unroll
            for (int k = 0; k < 9; ++k)
                acc[oc] = fmaf(v[k], w9[k], acc[oc]);
        }
    }

#pragma unroll
    for (int oc = 0; oc < 32; ++oc) {
        partial[(((size_t)ks * BB + b) * COUT + coutBase + oc) * (H * W) +
                (oy + py) * W + ox + px] = acc[oc];
    }
}

// Sum split-K partials + bias + ReLU
template<int C, int H, int W, int KS>
__global__ void conv_reduce(const float* __restrict__ partial,
                            const float* __restrict__ bias,
                            float* __restrict__ out)
{
    constexpr int TOTAL = BB * C * H * W;
    int idx = blockIdx.x * blockDim.x + threadIdx.x;
    if (idx >= TOTAL) return;
    int c = (idx / (H * W)) % C;
    float s = bias[c];
#pragma unroll
    for (int k = 0; k < KS; ++k)
        s += partial[(size_t)k * TOTAL + idx];
    out[idx] = fmaxf(s, 0.0f);
}

// ---------------------------------------------------------------------------
// Max pool KxK, stride K
// ---------------------------------------------------------------------------
template<int C, int H, int W, int K>
__global__ void maxpool_k(const float* __restrict__ in, float* __restrict__ out)
{
    constexpr int HO = H / K, WO = W / K;
    int idx = blockIdx.x * blockDim.x + threadIdx.x;
    constexpr int TOTAL = BB * C * HO * WO;
    if (idx >= TOTAL) return;
    int wo = idx % WO; int t = idx / WO;
    int ho = t % HO; t /= HO;
    int c = t % C; int b = t / C;
    const float* p = in + ((size_t)(b * C + c) * H + ho * K) * W + wo * K;
    float m = -INFINITY;
#pragma unroll
    for (int i = 0; i < K; ++i)
#pragma unroll
        for (int j = 0; j < K; ++j)
            m = fmaxf(m, p[i * W + j]);
    out[idx] = m;
}

// ---------------------------------------------------------------------------
// lin1: (64, 18432) @ (18432, 512), split-K partials.
// ---------------------------------------------------------------------------
constexpr int KSPLIT = 64;              // 18432 / 64 = 288 per split
__global__ __launch_bounds__(256)
void lin1_partial(const float* __restrict__ x, const float* __restrict__ w,
                  float* __restrict__ partial)
{
    const int j  = threadIdx.x % 64;
    const int bg = threadIdx.x / 64;          // 0..3
    const int jBase = blockIdx.x * 64;        // 8 tiles of 64
    const int k  = blockIdx.y;                // 0..63
    const int i0 = k * 288;

    __shared__ float s_x[32][64];

    float acc[16];
#pragma unroll
    for (int u = 0; u < 16; ++u) acc[u] = 0.0f;

    for (int ib = 0; ib < 288; ib += 32) {
        __syncthreads();
        {
            int lb = threadIdx.x / 4;           // b 0..63
            int lo = (threadIdx.x % 4) * 8;     // ii 0,8,16,24
            const float* src = x + (size_t)lb * HIDc + i0 + ib + lo;
            float4 a0 = *(const float4*)(src);
            float4 a1 = *(const float4*)(src + 4);
            float tmp[8] = {a0.x, a0.y, a0.z, a0.w, a1.x, a1.y, a1.z, a1.w};
#pragma unroll
            for (int r = 0; r < 8; ++r) s_x[lo + r][lb] = tmp[r];
        }
        __syncthreads();

        for (int ii = 0; ii < 32; ++ii) {
            float wv = w[(size_t)(i0 + ib + ii) * HIDLINc + jBase + j];
            const float4* xp = (const float4*)&s_x[ii][bg * 16];
            float4 x0 = xp[0], x1 = xp[1], x2 = xp[2], x3 = xp[3];
            acc[0]  = fmaf(x0.x, wv, acc[0]);
            acc[1]  = fmaf(x0.y, wv, acc[1]);
            acc[2]  = fmaf(x0.z, wv, acc[2]);
            acc[3]  = fmaf(x0.w, wv, acc[3]);
            acc[4]  = fmaf(x1.x, wv, acc[4]);
            acc[5]  = fmaf(x1.y, wv, acc[5]);
            acc[6]  = fmaf(x1.z, wv, acc[6]);
            acc[7]  = fmaf(x1.w, wv, acc[7]);
            acc[8]  = fmaf(x2.x, wv, acc[8]);
            acc[9]  = fmaf(x2.y, wv, acc[9]);
            acc[10] = fmaf(x2.z, wv, acc[10]);
            acc[11] = fmaf(x2.w, wv, acc[11]);
            acc[12] = fmaf(x3.x, wv, acc[12]);
            acc[13] = fmaf(x3.y, wv, acc[13]);
            acc[14] = fmaf(x3.z, wv, acc[14]);
            acc[15] = fmaf(x3.w, wv, acc[15]);
        }
    }

#pragma unroll
    for (int u = 0; u < 16; ++u) {
        int b = bg * 16 + u;
        partial[((size_t)k * 64 + b) * HIDLINc + jBase + j] = acc[u];
    }
}

__global__ void lin1_reduce(const float* __restrict__ partial,
                            const float* __restrict__ bias,
                            float* __restrict__ x1)
{
    int idx = blockIdx.x * blockDim.x + threadIdx.x;  // 64*512
    if (idx >= 64 * HIDLINc) return;
    int j = idx % HIDLINc;
    float s = 0.0f;
    for (int k = 0; k < KSPLIT; ++k)
        s += partial[(size_t)k * 64 * HIDLINc + idx];
    x1[idx] = fmaxf(s + bias[j], 0.0f);
}

// ---------------------------------------------------------------------------
// lin2: (64,512) @ (512,512) + bias + relu
// ---------------------------------------------------------------------------
__global__ __launch_bounds__(256)
void lin2_k(const float* __restrict__ x1, const float* __restrict__ w,
            const float* __restrict__ bias, float* __restrict__ x2)
{
    const int j  = threadIdx.x % 64;
    const int bl = threadIdx.x / 64;          // 0..3
    const int jBase = blockIdx.x * 64;        // 8
    const int b = blockIdx.y * 4 + bl;        // 16 groups of 4

    __shared__ float s_x[4][HIDLINc];
    for (int idx = threadIdx.x; idx < 4 * HIDLINc; idx += 256)
        s_x[idx / HIDLINc][idx % HIDLINc] =
            x1[(size_t)(blockIdx.y * 4 + idx / HIDLINc) * HIDLINc + idx % HIDLINc];
    __syncthreads();

    float acc = 0.0f;
    for (int i = 0; i < HIDLINc; ++i)
        acc = fmaf(s_x[bl][i], w[(size_t)i * HIDLINc + jBase + j], acc);
    x2[(size_t)b * HIDLINc + jBase + j] = fmaxf(acc + bias[jBase + j], 0.0f);
}

// ---------------------------------------------------------------------------
// lin3: (64,512) @ (512,24) + bias
// ---------------------------------------------------------------------------
__global__ void lin3_k(const float* __restrict__ x2, const float* __restrict__ w,
                       const float* __restrict__ bias, float* __restrict__ prep)
{
    int idx = blockIdx.x * blockDim.x + threadIdx.x;
    if (idx >= 64 * 24) return;
    int j = idx % 24, b = idx / 24;
    float acc = bias[j];
    for (int i = 0; i < HIDLINc; ++i)
        acc = fmaf(x2[(size_t)b * HIDLINc + i], w[i * 24 + j], acc);
    prep[idx] = acc;
}

// ---------------------------------------------------------------------------
// Head: means/sigmas/sample/points.  round = half-to-even (rintf)
// ---------------------------------------------------------------------------
__global__ void head_k(const float* __restrict__ prep, const float* __restrict__ noise,
                       float* __restrict__ outMeans, float* __restrict__ outSigmas,
                       int* __restrict__ pts)
{
    int id = blockIdx.x * blockDim.x + threadIdx.x;
    if (id >= BB * Gc) return;
    float m0 = prep[id * 3 + 0];
    float m1 = prep[id * 3 + 1];
    float sraw = prep[id * 3 + 2];
    float s = sraw + 2.0f;                       // SIGMA_BOOST
    float sig = fmaxf(s, 0.0f) + log1pf(expf(-fabsf(s)));
    sig += 1e-7f;                                // EPS
    float sg = sig * 95.0f;                      // (HI-1) == (WI-1)
    outMeans[id * 2 + 0] = m0;
    outMeans[id * 2 + 1] = m1;
    outSigmas[id * 2 + 0] = sg;
    outSigmas[id * 2 + 1] = sg;
    float sa0 = m0 + sg * noise[id * 2 + 0];
    float sa1 = m1 + sg * noise[id * 2 + 1];
    float t0 = 1.0f / (1.0f + expf(-sa0));
    float t1 = 1.0f / (1.0f + expf(-sa1));
    pts[id * 2 + 0] = (int)rintf(t0 * 79.0f);    // HI-HG-1
    pts[id * 2 + 1] = (int)rintf(t1 * 79.0f);    // WI-WG-1
}

// ---------------------------------------------------------------------------
// Patch extraction: copy (3,16,16) patch per (b,g)
// ---------------------------------------------------------------------------
__global__ __launch_bounds__(256)
void patch_k(const float* __restrict__ image, const int* __restrict__ pts,
             float* __restrict__ outR)
{
    int id = blockIdx.x;                  // b*G + g
    int b = id / Gc;
    int p0 = pts[id * 2 + 0];
    int p1 = pts[id * 2 + 1];
    for (int idx = threadIdx.x; idx < CIc * HGc * WGc; idx += 256) {
        int c = idx / (HGc * WGc), rem = idx % (HGc * WGc);
        int hh = rem / WGc, ww = rem % WGc;
        outR[(size_t)id * (CIc * HGc * WGc) + idx] =
            image[((size_t)(b * CIc + c) * HIc + p0 + hh) * WIc + p1 + ww];
    }
}

// ---------------------------------------------------------------------------
extern "C" void kernel_launch(void* const* d_in, const int* in_sizes, int n_in,
                              void* d_out, int out_size, void* d_ws, size_t ws_size,
                              hipStream_t stream)
{
    const float* image = (const float*)d_in[0];
    const float* noise = (const float*)d_in[1];
    const float* w1a = (const float*)d_in[2];
    const float* b1a = (const float*)d_in[3];
    const float* w1b = (const float*)d_in[4];
    const float* b1b = (const float*)d_in[5];
    const float* w2a = (const float*)d_in[6];
    const float* b2a = (const float*)d_in[7];
    const float* w2b = (const float*)d_in[8];
    const float* b2b = (const float*)d_in[9];
    const float* w3a = (const float*)d_in[10];
    const float* b3a = (const float*)d_in[11];
    const float* w3b = (const float*)d_in[12];
    const float* b3b = (const float*)d_in[13];
    const float* wl1 = (const float*)d_in[14];
    const float* bl1 = (const float*)d_in[15];
    const float* wl2 = (const float*)d_in[16];
    const float* bl2 = (const float*)d_in[17];
    const float* wl3 = (const float*)d_in[18];
    const float* bl3 = (const float*)d_in[19];

    float* out = (float*)d_out;
    float* ws  = (float*)d_ws;

    // Workspace layout (floats): two big regions A,B of 18,874,368 floats.
    constexpr size_t BIGF = (size_t)BB * 32 * HIc * WIc;   // 18,874,368 floats
    constexpr size_t MF = 1u << 20;
    float* A  = ws;
    float* Bf = ws + BIGF;
    float* t0   = A;                 // pool1 out      (1,179,648)
    float* t1   = A + 2 * MF;        // conv2a out     (2,359,296)
    float* t2   = A + 5 * MF;        // conv2b out     (2,359,296)
    float* t3   = A + 8 * MF;        // pool2 out        (589,824)
    float* t4   = A + 9 * MF;        // conv3a out     (1,179,648)
    float* t5   = A + 11 * MF;       // conv3b out / x (1,179,648)
    float* part = A + 13 * MF;       // lin1 partials  (2,097,152)
    float* x1   = A + 16 * MF;       // 32768
    float* x2   = x1 + 64 * HIDLINc; // 32768
    float* prep = x2 + 64 * HIDLINc; // 1536
    int*   pts  = (int*)(prep + 2048);

    // conv1a: image(64,3,96,96) -> A(64,32,96,96)
    conv3x3_relu<3, 32, 96, 96, 8, 32, 3>
        <<<dim3(36, 64, 1), 256, 0, stream>>>(image, w1a, b1a, A);
    // conv1b: A -> B (64,32,96,96)  -- new weight-amortized design
    conv1b_v3<<<dim3(6, 64, 4), 192, 0, stream>>>(A, w1b, b1b, Bf);
    // pool 4x4: B -> t0 (64,32,24,24)
    maxpool_k<32, 96, 96, 4>
        <<<(BB * 32 * 24 * 24 + 255) / 256, 256, 0, stream>>>(Bf, t0);

    // conv2a: t0 -> partial(B) -> t1 (64,64,24,24); KS=2
    conv3x3_split<32, 64, 24, 24, 8, 24, 2>
        <<<dim3(3, 64, 2 * 2), 192, 0, stream>>>(t0, w2a, Bf);
    conv_reduce<64, 24, 24, 2>
        <<<(BB * 64 * 576 + 255) / 256, 256, 0, stream>>>(Bf, b2a, t1);

    // conv2b: t1 -> partial(B) -> t2; KS=4
    conv3x3_split<64, 64, 24, 24, 8, 24, 4>
        <<<dim3(3, 64, 2 * 4), 192, 0, stream>>>(t1, w2b, Bf);
    conv_reduce<64, 24, 24, 4>
        <<<(BB * 64 * 576 + 255) / 256, 256, 0, stream>>>(Bf, b2b, t2);

    // pool 2x2: t2 -> t3 (64,64,12,12)
    maxpool_k<64, 24, 24, 2>
        <<<(BB * 64 * 12 * 12 + 255) / 256, 256, 0, stream>>>(t2, t3);

    // conv3a: t3 -> partial(B) -> t4 (64,128,12,12); KS=4
    conv3x3_split<64, 128, 12, 12, 12, 12, 4>
        <<<dim3(1, 64, 4 * 4), 144, 0, stream>>>(t3, w3a, Bf);
    conv_reduce<128, 12, 12, 4>
        <<<(BB * 128 * 144 + 255) / 256, 256, 0, stream>>>(Bf, b3a, t4);

    // conv3b: t4 -> partial(B) -> t5; KS=8 -> 2048 blocks
    conv3x3_split<128, 128, 12, 12, 12, 12, 8>
        <<<dim3(1, 64, 4 * 8), 144, 0, stream>>>(t4, w3b, Bf);
    conv_reduce<128, 12, 12, 8>
        <<<(BB * 128 * 144 + 255) / 256, 256, 0, stream>>>(Bf, b3b, t5);

    // lin1: x @ wl1 (+bl1, relu) via split-K
    lin1_partial<<<dim3(8, KSPLIT), 256, 0, stream>>>(t5, wl1, part);
    lin1_reduce<<<(64 * HIDLINc + 255) / 256, 256, 0, stream>>>(part, bl1, x1);
    // lin2
    lin2_k<<<dim3(8, 16), 256, 0, stream>>>(x1, wl2, bl2, x2);
    // lin3 -> prep (64,24)
    lin3_k<<<6, 256, 0, stream>>>(x2, wl3, bl3, prep);
    // head -> means/sigmas into out, pts into ws
    head_k<<<2, 256, 0, stream>>>(prep, noise,
                                  out + (size_t)BB * Gc * CIc * HGc * WGc,
                                  out + (size_t)BB * Gc * CIc * HGc * WGc + BB * Gc * 2,
                                  pts);
    // patch extraction -> out[0 .. 393216)
    patch_k<<<BB * Gc, 256, 0, stream>>>(image, pts, out);
}

// Round 5
// 838.616 us; speedup vs baseline: 1.7216x; 1.2064x over previous
//
#include <hip/hip_runtime.h>
#include <math.h>

// Problem constants
constexpr int BB  = 64;    // batch
constexpr int CIc = 3;     // image channels
constexpr int HIc = 96, WIc = 96;
constexpr int Gc  = 8, HGc = 16, WGc = 16;
constexpr int HIDc = 18432;      // 128*12*12
constexpr int HIDLINc = 512;

// ---------------------------------------------------------------------------
// conv96_v4: 3x3 conv pad=1 on 96x96, COUT=32, all oc in one block.
// Block 256 = 32 cols x 8 row-groups; each thread: 2 rows x 32 oc (64 acc).
// Input staged row-major [CBLK][18][34] (coalesced, conflict-free);
// weights read from wave-uniform global addresses -> compiler emits s_load,
// FMAs take the weight as an SGPR operand (proven by round-2 counters).
// Per ci per thread: 12 ds_read + 576 FMA.
// Grid: (18 tiles = 3x x 6y, batch)
// ---------------------------------------------------------------------------
template<int CIN, int CBLK>
__global__ __launch_bounds__(256)
void conv96_v4(const float* __restrict__ in, const float* __restrict__ wgt,
               const float* __restrict__ bias, float* __restrict__ out)
{
    const int tile = blockIdx.x;
    const int txi = tile % 3, tyi = tile / 3;
    const int ox = txi * 32, oy = tyi * 16;
    const int b = blockIdx.y;
    const int tid = threadIdx.x;
    const int px = tid & 31;          // col 0..31
    const int py = tid >> 5;          // 0..7 -> rows 2py, 2py+1

    __shared__ float s_in[CBLK][18][34];

    float acc0[32], acc1[32];
#pragma unroll
    for (int oc = 0; oc < 32; ++oc) { acc0[oc] = 0.0f; acc1[oc] = 0.0f; }

    for (int cb = 0; cb < CIN; cb += CBLK) {
        __syncthreads();
        constexpr int TOT = CBLK * 18 * 34;
        for (int idx = tid; idx < TOT; idx += 256) {
            int ci  = idx / (18 * 34);
            int rem = idx - ci * (18 * 34);
            int r = rem / 34;
            int c = rem - r * 34;
            int gy = oy + r - 1, gx = ox + c - 1;
            float v = 0.0f;
            if (gy >= 0 && gy < 96 && gx >= 0 && gx < 96)
                v = in[((size_t)(b * CIN + cb + ci) * 96 + gy) * 96 + gx];
            s_in[ci][r][c] = v;
        }
        __syncthreads();

        for (int ci = 0; ci < CBLK; ++ci) {
            float v[4][3];
#pragma unroll
            for (int r = 0; r < 4; ++r)
#pragma unroll
                for (int c = 0; c < 3; ++c)
                    v[r][c] = s_in[ci][2 * py + r][px + c];

#pragma unroll
            for (int oc = 0; oc < 32; ++oc) {
                const float* w9 = wgt + ((size_t)oc * CIN + (cb + ci)) * 9;
                float a0 = acc0[oc], a1 = acc1[oc];
#pragma unroll
                for (int dy = 0; dy < 3; ++dy)
#pragma unroll
                    for (int dx = 0; dx < 3; ++dx) {
                        float wv = w9[dy * 3 + dx];
                        a0 = fmaf(v[dy][dx],     wv, a0);
                        a1 = fmaf(v[dy + 1][dx], wv, a1);
                    }
                acc0[oc] = a0; acc1[oc] = a1;
            }
        }
    }

#pragma unroll
    for (int oc = 0; oc < 32; ++oc) {
        float bv = bias[oc];
        size_t base = ((size_t)(b * 32 + oc) * 96 + oy + 2 * py) * 96 + ox + px;
        out[base]      = fmaxf(acc0[oc] + bv, 0.0f);
        out[base + 96] = fmaxf(acc1[oc] + bv, 0.0f);
    }
}

// ---------------------------------------------------------------------------
// Split-K direct 3x3 conv (round-2 form): partials [KS][B][COUT][H][W].
// ---------------------------------------------------------------------------
template<int CIN, int COUT, int H, int W, int TH, int TW, int KS>
__global__ __launch_bounds__(TH * TW)
void conv3x3_split(const float* __restrict__ in, const float* __restrict__ wgt,
                   float* __restrict__ partial)
{
    constexpr int CBLK = CIN / KS;
    constexpr int NTX = W / TW;
    const int tx = blockIdx.x % NTX, ty = blockIdx.x / NTX;
    const int b  = blockIdx.y;
    const int chunk = blockIdx.z / KS;
    const int ks    = blockIdx.z % KS;
    const int coutBase = chunk * 32;
    const int cinBase  = ks * CBLK;
    const int tid = threadIdx.x;
    const int px = tid % TW, py = tid / TW;
    const int ox = tx * TW, oy = ty * TH;

    __shared__ float s_in[CBLK][TH + 2][TW + 2];

    constexpr int TOT = CBLK * (TH + 2) * (TW + 2);
    for (int idx = tid; idx < TOT; idx += TH * TW) {
        int ci  = idx / ((TH + 2) * (TW + 2));
        int rem = idx % ((TH + 2) * (TW + 2));
        int yy = rem / (TW + 2), xx = rem % (TW + 2);
        int gy = oy + yy - 1, gx = ox + xx - 1;
        float v = 0.0f;
        if (gy >= 0 && gy < H && gx >= 0 && gx < W)
            v = in[((size_t)(b * CIN + cinBase + ci) * H + gy) * W + gx];
        s_in[ci][yy][xx] = v;
    }
    __syncthreads();

    float acc[32];
#pragma unroll
    for (int oc = 0; oc < 32; ++oc) acc[oc] = 0.0f;

    for (int ci = 0; ci < CBLK; ++ci) {
        float v[9];
#pragma unroll
        for (int dy = 0; dy < 3; ++dy)
#pragma unroll
            for (int dx = 0; dx < 3; ++dx)
                v[dy * 3 + dx] = s_in[ci][py + dy][px + dx];

#pragma unroll
        for (int oc = 0; oc < 32; ++oc) {
            const float* w9 =
                wgt + ((size_t)(coutBase + oc) * CIN + (cinBase + ci)) * 9;
#pragma unroll
            for (int k = 0; k < 9; ++k)
                acc[oc] = fmaf(v[k], w9[k], acc[oc]);
        }
    }

#pragma unroll
    for (int oc = 0; oc < 32; ++oc) {
        partial[(((size_t)ks * BB + b) * COUT + coutBase + oc) * (H * W) +
                (oy + py) * W + ox + px] = acc[oc];
    }
}

// Sum split-K partials + bias + ReLU
template<int C, int H, int W, int KS>
__global__ void conv_reduce(const float* __restrict__ partial,
                            const float* __restrict__ bias,
                            float* __restrict__ out)
{
    constexpr int TOTAL = BB * C * H * W;
    int idx = blockIdx.x * blockDim.x + threadIdx.x;
    if (idx >= TOTAL) return;
    int c = (idx / (H * W)) % C;
    float s = bias[c];
#pragma unroll
    for (int k = 0; k < KS; ++k)
        s += partial[(size_t)k * TOTAL + idx];
    out[idx] = fmaxf(s, 0.0f);
}

// ---------------------------------------------------------------------------
// Max pool KxK, stride K
// ---------------------------------------------------------------------------
template<int C, int H, int W, int K>
__global__ void maxpool_k(const float* __restrict__ in, float* __restrict__ out)
{
    constexpr int HO = H / K, WO = W / K;
    int idx = blockIdx.x * blockDim.x + threadIdx.x;
    constexpr int TOTAL = BB * C * HO * WO;
    if (idx >= TOTAL) return;
    int wo = idx % WO; int t = idx / WO;
    int ho = t % HO; t /= HO;
    int c = t % C; int b = t / C;
    const float* p = in + ((size_t)(b * C + c) * H + ho * K) * W + wo * K;
    float m = -INFINITY;
#pragma unroll
    for (int i = 0; i < K; ++i)
#pragma unroll
        for (int j = 0; j < K; ++j)
            m = fmaxf(m, p[i * W + j]);
    out[idx] = m;
}

// ---------------------------------------------------------------------------
// lin1: (64, 18432) @ (18432, 512), split-K partials.
// ---------------------------------------------------------------------------
constexpr int KSPLIT = 64;              // 18432 / 64 = 288 per split
__global__ __launch_bounds__(256)
void lin1_partial(const float* __restrict__ x, const float* __restrict__ w,
                  float* __restrict__ partial)
{
    const int j  = threadIdx.x % 64;
    const int bg = threadIdx.x / 64;          // 0..3
    const int jBase = blockIdx.x * 64;        // 8 tiles of 64
    const int k  = blockIdx.y;                // 0..63
    const int i0 = k * 288;

    __shared__ float s_x[32][64];

    float acc[16];
#pragma unroll
    for (int u = 0; u < 16; ++u) acc[u] = 0.0f;

    for (int ib = 0; ib < 288; ib += 32) {
        __syncthreads();
        {
            int lb = threadIdx.x / 4;           // b 0..63
            int lo = (threadIdx.x % 4) * 8;     // ii 0,8,16,24
            const float* src = x + (size_t)lb * HIDc + i0 + ib + lo;
            float4 a0 = *(const float4*)(src);
            float4 a1 = *(const float4*)(src + 4);
            float tmp[8] = {a0.x, a0.y, a0.z, a0.w, a1.x, a1.y, a1.z, a1.w};
#pragma unroll
            for (int r = 0; r < 8; ++r) s_x[lo + r][lb] = tmp[r];
        }
        __syncthreads();

        for (int ii = 0; ii < 32; ++ii) {
            float wv = w[(size_t)(i0 + ib + ii) * HIDLINc + jBase + j];
            const float4* xp = (const float4*)&s_x[ii][bg * 16];
            float4 x0 = xp[0], x1 = xp[1], x2 = xp[2], x3 = xp[3];
            acc[0]  = fmaf(x0.x, wv, acc[0]);
            acc[1]  = fmaf(x0.y, wv, acc[1]);
            acc[2]  = fmaf(x0.z, wv, acc[2]);
            acc[3]  = fmaf(x0.w, wv, acc[3]);
            acc[4]  = fmaf(x1.x, wv, acc[4]);
            acc[5]  = fmaf(x1.y, wv, acc[5]);
            acc[6]  = fmaf(x1.z, wv, acc[6]);
            acc[7]  = fmaf(x1.w, wv, acc[7]);
            acc[8]  = fmaf(x2.x, wv, acc[8]);
            acc[9]  = fmaf(x2.y, wv, acc[9]);
            acc[10] = fmaf(x2.z, wv, acc[10]);
            acc[11] = fmaf(x2.w, wv, acc[11]);
            acc[12] = fmaf(x3.x, wv, acc[12]);
            acc[13] = fmaf(x3.y, wv, acc[13]);
            acc[14] = fmaf(x3.z, wv, acc[14]);
            acc[15] = fmaf(x3.w, wv, acc[15]);
        }
    }

#pragma unroll
    for (int u = 0; u < 16; ++u) {
        int b = bg * 16 + u;
        partial[((size_t)k * 64 + b) * HIDLINc + jBase + j] = acc[u];
    }
}

__global__ void lin1_reduce(const float* __restrict__ partial,
                            const float* __restrict__ bias,
                            float* __restrict__ x1)
{
    int idx = blockIdx.x * blockDim.x + threadIdx.x;  // 64*512
    if (idx >= 64 * HIDLINc) return;
    int j = idx % HIDLINc;
    float s = 0.0f;
    for (int k = 0; k < KSPLIT; ++k)
        s += partial[(size_t)k * 64 * HIDLINc + idx];
    x1[idx] = fmaxf(s + bias[j], 0.0f);
}

// ---------------------------------------------------------------------------
// lin2: (64,512) @ (512,512) + bias + relu
// ---------------------------------------------------------------------------
__global__ __launch_bounds__(256)
void lin2_k(const float* __restrict__ x1, const float* __restrict__ w,
            const float* __restrict__ bias, float* __restrict__ x2)
{
    const int j  = threadIdx.x % 64;
    const int bl = threadIdx.x / 64;          // 0..3
    const int jBase = blockIdx.x * 64;        // 8
    const int b = blockIdx.y * 4 + bl;        // 16 groups of 4

    __shared__ float s_x[4][HIDLINc];
    for (int idx = threadIdx.x; idx < 4 * HIDLINc; idx += 256)
        s_x[idx / HIDLINc][idx % HIDLINc] =
            x1[(size_t)(blockIdx.y * 4 + idx / HIDLINc) * HIDLINc + idx % HIDLINc];
    __syncthreads();

    float acc = 0.0f;
    for (int i = 0; i < HIDLINc; ++i)
        acc = fmaf(s_x[bl][i], w[(size_t)i * HIDLINc + jBase + j], acc);
    x2[(size_t)b * HIDLINc + jBase + j] = fmaxf(acc + bias[jBase + j], 0.0f);
}

// ---------------------------------------------------------------------------
// lin3: (64,512) @ (512,24) + bias
// ---------------------------------------------------------------------------
__global__ void lin3_k(const float* __restrict__ x2, const float* __restrict__ w,
                       const float* __restrict__ bias, float* __restrict__ prep)
{
    int idx = blockIdx.x * blockDim.x + threadIdx.x;
    if (idx >= 64 * 24) return;
    int j = idx % 24, b = idx / 24;
    float acc = bias[j];
    for (int i = 0; i < HIDLINc; ++i)
        acc = fmaf(x2[(size_t)b * HIDLINc + i], w[i * 24 + j], acc);
    prep[idx] = acc;
}

// ---------------------------------------------------------------------------
// Head: means/sigmas/sample/points.  round = half-to-even (rintf)
// ---------------------------------------------------------------------------
__global__ void head_k(const float* __restrict__ prep, const float* __restrict__ noise,
                       float* __restrict__ outMeans, float* __restrict__ outSigmas,
                       int* __restrict__ pts)
{
    int id = blockIdx.x * blockDim.x + threadIdx.x;
    if (id >= BB * Gc) return;
    float m0 = prep[id * 3 + 0];
    float m1 = prep[id * 3 + 1];
    float sraw = prep[id * 3 + 2];
    float s = sraw + 2.0f;                       // SIGMA_BOOST
    float sig = fmaxf(s, 0.0f) + log1pf(expf(-fabsf(s)));
    sig += 1e-7f;                                // EPS
    float sg = sig * 95.0f;                      // (HI-1) == (WI-1)
    outMeans[id * 2 + 0] = m0;
    outMeans[id * 2 + 1] = m1;
    outSigmas[id * 2 + 0] = sg;
    outSigmas[id * 2 + 1] = sg;
    float sa0 = m0 + sg * noise[id * 2 + 0];
    float sa1 = m1 + sg * noise[id * 2 + 1];
    float t0 = 1.0f / (1.0f + expf(-sa0));
    float t1 = 1.0f / (1.0f + expf(-sa1));
    pts[id * 2 + 0] = (int)rintf(t0 * 79.0f);    // HI-HG-1
    pts[id * 2 + 1] = (int)rintf(t1 * 79.0f);    // WI-WG-1
}

// ---------------------------------------------------------------------------
// Patch extraction: copy (3,16,16) patch per (b,g)
// ---------------------------------------------------------------------------
__global__ __launch_bounds__(256)
void patch_k(const float* __restrict__ image, const int* __restrict__ pts,
             float* __restrict__ outR)
{
    int id = blockIdx.x;                  // b*G + g
    int b = id / Gc;
    int p0 = pts[id * 2 + 0];
    int p1 = pts[id * 2 + 1];
    for (int idx = threadIdx.x; idx < CIc * HGc * WGc; idx += 256) {
        int c = idx / (HGc * WGc), rem = idx % (HGc * WGc);
        int hh = rem / WGc, ww = rem % WGc;
        outR[(size_t)id * (CIc * HGc * WGc) + idx] =
            image[((size_t)(b * CIc + c) * HIc + p0 + hh) * WIc + p1 + ww];
    }
}

// ---------------------------------------------------------------------------
extern "C" void kernel_launch(void* const* d_in, const int* in_sizes, int n_in,
                              void* d_out, int out_size, void* d_ws, size_t ws_size,
                              hipStream_t stream)
{
    const float* image = (const float*)d_in[0];
    const float* noise = (const float*)d_in[1];
    const float* w1a = (const float*)d_in[2];
    const float* b1a = (const float*)d_in[3];
    const float* w1b = (const float*)d_in[4];
    const float* b1b = (const float*)d_in[5];
    const float* w2a = (const float*)d_in[6];
    const float* b2a = (const float*)d_in[7];
    const float* w2b = (const float*)d_in[8];
    const float* b2b = (const float*)d_in[9];
    const float* w3a = (const float*)d_in[10];
    const float* b3a = (const float*)d_in[11];
    const float* w3b = (const float*)d_in[12];
    const float* b3b = (const float*)d_in[13];
    const float* wl1 = (const float*)d_in[14];
    const float* bl1 = (const float*)d_in[15];
    const float* wl2 = (const float*)d_in[16];
    const float* bl2 = (const float*)d_in[17];
    const float* wl3 = (const float*)d_in[18];
    const float* bl3 = (const float*)d_in[19];

    float* out = (float*)d_out;
    float* ws  = (float*)d_ws;

    // Workspace layout (floats): two big regions A,B of 18,874,368 floats.
    constexpr size_t BIGF = (size_t)BB * 32 * HIc * WIc;   // 18,874,368 floats
    constexpr size_t MF = 1u << 20;
    float* A  = ws;
    float* Bf = ws + BIGF;
    float* t0   = A;                 // pool1 out      (1,179,648)
    float* t1   = A + 2 * MF;        // conv2a out     (2,359,296)
    float* t2   = A + 5 * MF;        // conv2b out     (2,359,296)
    float* t3   = A + 8 * MF;        // pool2 out        (589,824)
    float* t4   = A + 9 * MF;        // conv3a out     (1,179,648)
    float* t5   = A + 11 * MF;       // conv3b out / x (1,179,648)
    float* part = A + 13 * MF;       // lin1 partials  (2,097,152)
    float* x1   = A + 16 * MF;       // 32768
    float* x2   = x1 + 64 * HIDLINc; // 32768
    float* prep = x2 + 64 * HIDLINc; // 1536
    int*   pts  = (int*)(prep + 2048);

    // conv1a: image(64,3,96,96) -> A(64,32,96,96)
    conv96_v4<3, 3><<<dim3(18, 64), 256, 0, stream>>>(image, w1a, b1a, A);
    // conv1b: A -> B (64,32,96,96)
    conv96_v4<32, 8><<<dim3(18, 64), 256, 0, stream>>>(A, w1b, b1b, Bf);
    // pool 4x4: B -> t0 (64,32,24,24)
    maxpool_k<32, 96, 96, 4>
        <<<(BB * 32 * 24 * 24 + 255) / 256, 256, 0, stream>>>(Bf, t0);

    // conv2a: t0 -> partial(B) -> t1 (64,64,24,24); KS=2
    conv3x3_split<32, 64, 24, 24, 8, 24, 2>
        <<<dim3(3, 64, 2 * 2), 192, 0, stream>>>(t0, w2a, Bf);
    conv_reduce<64, 24, 24, 2>
        <<<(BB * 64 * 576 + 255) / 256, 256, 0, stream>>>(Bf, b2a, t1);

    // conv2b: t1 -> partial(B) -> t2; KS=4
    conv3x3_split<64, 64, 24, 24, 8, 24, 4>
        <<<dim3(3, 64, 2 * 4), 192, 0, stream>>>(t1, w2b, Bf);
    conv_reduce<64, 24, 24, 4>
        <<<(BB * 64 * 576 + 255) / 256, 256, 0, stream>>>(Bf, b2b, t2);

    // pool 2x2: t2 -> t3 (64,64,12,12)
    maxpool_k<64, 24, 24, 2>
        <<<(BB * 64 * 12 * 12 + 255) / 256, 256, 0, stream>>>(t2, t3);

    // conv3a: t3 -> partial(B) -> t4 (64,128,12,12); KS=4
    conv3x3_split<64, 128, 12, 12, 12, 12, 4>
        <<<dim3(1, 64, 4 * 4), 144, 0, stream>>>(t3, w3a, Bf);
    conv_reduce<128, 12, 12, 4>
        <<<(BB * 128 * 144 + 255) / 256, 256, 0, stream>>>(Bf, b3a, t4);

    // conv3b: t4 -> partial(B) -> t5; KS=8
    conv3x3_split<128, 128, 12, 12, 12, 12, 8>
        <<<dim3(1, 64, 4 * 8), 144, 0, stream>>>(t4, w3b, Bf);
    conv_reduce<128, 12, 12, 8>
        <<<(BB * 128 * 144 + 255) / 256, 256, 0, stream>>>(Bf, b3b, t5);

    // lin1: x @ wl1 (+bl1, relu) via split-K
    lin1_partial<<<dim3(8, KSPLIT), 256, 0, stream>>>(t5, wl1, part);
    lin1_reduce<<<(64 * HIDLINc + 255) / 256, 256, 0, stream>>>(part, bl1, x1);
    // lin2
    lin2_k<<<dim3(8, 16), 256, 0, stream>>>(x1, wl2, bl2, x2);
    // lin3 -> prep (64,24)
    lin3_k<<<6, 256, 0, stream>>>(x2, wl3, bl3, prep);
    // head -> means/sigmas into out, pts into ws
    head_k<<<2, 256, 0, stream>>>(prep, noise,
                                  out + (size_t)BB * Gc * CIc * HGc * WGc,
                                  out + (size_t)BB * Gc * CIc * HGc * WGc + BB * Gc * 2,
                                  pts);
    // patch extraction -> out[0 .. 393216)
    patch_k<<<BB * Gc, 256, 0, stream>>>(image, pts, out);
}